// Round 5
// baseline (230.525 us; speedup 1.0000x reference)
//
#include <hip/hip_runtime.h>
#include <stdint.h>

#define NB 2
#define NC 34
#define HH 512
#define WW 1024
#define HWW (HH*WW)
#define KK 200
#define CAP 32768
#define MCAP 4096
#define LCAP 512

// NMS tiling
#define TW 128
#define TH 16
#define HALO 3

// ---------------------------------------------------------------- init ws
__global__ void __launch_bounds__(256) k_init(uint32_t* cnt, uint32_t* counts, float* sums) {
    int t = blockIdx.x * 256 + threadIdx.x;
    if (t < NB) cnt[t] = 0u;
    if (t < NB * (KK + 1) * NC) counts[t] = 0u;
    if (t < NB * (KK + 1)) sums[t] = 0.f;
}

// ------------------------------------------- per-pixel argmax + softmax stats
__global__ void __launch_bounds__(256) k_seg(const float* __restrict__ logits,
                                             float* __restrict__ segs_out,
                                             float* __restrict__ smax,
                                             float* __restrict__ sden,
                                             int use_stats) {
    int t = blockIdx.x * 256 + threadIdx.x;   // t < NB*HWW/2
    if (t >= NB * HWW / 2) return;
    int p = t * 2;
    int b = p / HWW, r = p - b * HWW;
    const float* base = logits + (size_t)b * NC * HWW + r;
    float2 v[NC];
    float m0 = -3e38f, m1 = -3e38f;
    int a0 = 0, a1 = 0;
#pragma unroll
    for (int c = 0; c < NC; ++c) {
        v[c] = *(const float2*)(base + (size_t)c * HWW);
        if (v[c].x > m0) { m0 = v[c].x; a0 = c; }
        if (v[c].y > m1) { m1 = v[c].y; a1 = c; }
    }
    float s0 = 0.f, s1 = 0.f;
#pragma unroll
    for (int c = 0; c < NC; ++c) {
        s0 += __expf(v[c].x - m0);
        s1 += __expf(v[c].y - m1);
    }
    *(float2*)(segs_out + p) = make_float2((float)a0, (float)a1);
    if (use_stats) {
        *(float2*)(smax + p) = make_float2(m0, m1);
        *(float2*)(sden + p) = make_float2(s0, s1);
    }
}

// ----------------- NMS: separable 7x7 max via LDS + per-block candidate compaction
__global__ void __launch_bounds__(256) k_nms(const float* __restrict__ cmap,
                                             uint64_t* __restrict__ cand,
                                             uint32_t* __restrict__ cnt) {
    __shared__ float sIn[TH + 2 * HALO][TW + 2 * HALO];   // 22 x 134
    __shared__ float sH[TH + 2 * HALO][TW];               // 22 x 128
    __shared__ uint64_t lc[LCAP];
    __shared__ uint32_t lcnt, gbase;
    int t = blockIdx.x;
    int bx = t & (WW / TW - 1);          // 0..7
    int by = (t >> 3) & (HH / TH - 1);   // 0..31
    int b = t >> 8;                      // 0..NB-1
    int tid = threadIdx.x;
    const float* bb = cmap + (size_t)b * HWW;
    if (tid == 0) lcnt = 0u;

    const int LW = TW + 2 * HALO;                 // 134
    const int LH = TH + 2 * HALO;                 // 22
    for (int idx = tid; idx < LW * LH; idx += 256) {
        int r = idx / LW, c = idx - r * LW;
        int gh = by * TH + r - HALO;
        int gw = bx * TW + c - HALO;
        float v = -3e38f;
        if (gh >= 0 && gh < HH && gw >= 0 && gw < WW) v = bb[gh * WW + gw];
        sIn[r][c] = v;
    }
    __syncthreads();

    // horizontal 1x7 max
    for (int idx = tid; idx < LH * TW; idx += 256) {
        int r = idx / TW, c = idx - r * TW;
        float m = fmaxf(fmaxf(fmaxf(sIn[r][c], sIn[r][c + 1]),
                              fmaxf(sIn[r][c + 2], sIn[r][c + 3])),
                        fmaxf(fmaxf(sIn[r][c + 4], sIn[r][c + 5]), sIn[r][c + 6]));
        sH[r][c] = m;
    }
    __syncthreads();

    // vertical 7x1 max + candidate test -> LDS compaction
    for (int idx = tid; idx < TH * TW; idx += 256) {
        int r = idx >> 7, c = idx & (TW - 1);
        float cv = sIn[r + HALO][c + HALO];
        float m = fmaxf(fmaxf(fmaxf(sH[r][c], sH[r + 1][c]),
                              fmaxf(sH[r + 2][c], sH[r + 3][c])),
                        fmaxf(fmaxf(sH[r + 4][c], sH[r + 5][c]), sH[r + 6][c]));
        if (m > 0.1f && cv == m) {
            int gh = by * TH + r;
            int gw = bx * TW + c;
            uint32_t rr = (uint32_t)(gh * WW + gw);
            uint32_t pos = atomicAdd(&lcnt, 1u);   // LDS atomic: per-CU, fast
            if (pos < LCAP)
                lc[pos] = ((uint64_t)__float_as_uint(cv) << 32) |
                          (uint64_t)(0xFFFFFFFFu - rr);
        }
    }
    __syncthreads();
    uint32_t n = lcnt;
    if (n > LCAP) n = LCAP;
    if (tid == 0 && n) gbase = atomicAdd(&cnt[b], n);   // ONE global atomic per block
    __syncthreads();
    for (uint32_t i = tid; i < n; i += 256) {
        uint32_t pos = gbase + i;
        if (pos < CAP) cand[(size_t)b * CAP + pos] = lc[i];
    }
}

// ------------------------- exact top-K: radix-select on float bits + exact rank
// 1024 threads; wave-aggregated histogram atomics (data is value-concentrated).
__global__ void __launch_bounds__(1024) k_topk(const uint64_t* __restrict__ cand,
                                               const uint32_t* __restrict__ cnt,
                                               float* __restrict__ probs_out,
                                               float* __restrict__ cxy) {
    int b = blockIdx.x;
    int tid = threadIdx.x;
    int lane = tid & 63;
    __shared__ uint32_t shist[256];
    __shared__ uint64_t lkey[MCAP];
    __shared__ uint32_t lM, sPrefix, sNeed;

    if (tid < KK) {
        probs_out[b * KK + tid] = 0.f;
        cxy[(b * KK + tid) * 2]     = 1e19f;  // invalid -> huge coords -> inf dist
        cxy[(b * KK + tid) * 2 + 1] = 1e19f;
    }
    if (tid == 0) { lM = 0u; sPrefix = 0u; sNeed = KK; }
    uint32_t N = cnt[b];
    if (N > CAP) N = CAP;
    uint32_t Nround = (N + 1023u) & ~1023u;   // uniform trip count (wave-safe ballots)
    __syncthreads();

    uint32_t T = 0u;
    if (N > KK) {
        const uint64_t* cb = cand + (size_t)b * CAP;
        for (int shift = 24; shift >= 0; shift -= 8) {
            if (tid < 256) shist[tid] = 0u;
            __syncthreads();
            uint32_t prefix = sPrefix;
            uint32_t mask = (shift == 24) ? 0u : (0xFFFFFFFFu << (shift + 8));
            for (uint32_t i = tid; i < Nround; i += 1024) {
                uint32_t k32 = 0u;
                if (i < N) k32 = (uint32_t)(cb[i] >> 32);
                uint32_t digit = (k32 >> shift) & 255u;
                bool mine = (i < N) && ((k32 & mask) == prefix);
                // wave-aggregate same-digit atomics (capped match loop)
#pragma unroll 1
                for (int it = 0; it < 6; ++it) {
                    uint64_t m64 = __ballot(mine);
                    if (!m64) break;
                    int leader = __ffsll((unsigned long long)m64) - 1;
                    uint32_t dl = __shfl(digit, leader, 64);
                    uint64_t same = __ballot(mine && (digit == dl));
                    if (lane == leader)
                        atomicAdd(&shist[dl], (uint32_t)__popcll((unsigned long long)same));
                    mine = mine && (digit != dl);
                }
                if (mine) atomicAdd(&shist[digit], 1u);
            }
            __syncthreads();
            if (tid == 0) {
                uint32_t need = sNeed, cum = 0u;
                int sel = 0;
                for (int d = 255; d >= 0; --d) {
                    uint32_t c = shist[d];
                    if (cum + c >= need) { sel = d; sNeed = need - cum; break; }
                    cum += c;
                }
                sPrefix = prefix | ((uint32_t)sel << shift);
            }
            __syncthreads();
        }
        T = sPrefix;   // exact float-bit pattern of the KK-th largest value
    }

    // collect all candidates with value-bits >= T (M = KK + exact-value ties)
    {
        const uint64_t* cb = cand + (size_t)b * CAP;
        for (uint32_t i = tid; i < N; i += 1024) {
            uint64_t kk = cb[i];
            if ((uint32_t)(kk >> 32) >= T) {
                uint32_t pos = atomicAdd(&lM, 1u);
                if (pos < MCAP) lkey[pos] = kk;
            }
        }
    }
    __syncthreads();
    uint32_t M = lM;
    if (M > MCAP) M = MCAP;
    // exact global rank (desc value, asc index via ~idx in low bits)
    for (uint32_t i = tid; i < M; i += 1024) {
        uint64_t kk = lkey[i];
        uint32_t rank = 0;
        for (uint32_t j = 0; j < M; ++j) rank += (lkey[j] > kk) ? 1u : 0u;
        if (rank < KK) {
            uint32_t bits = (uint32_t)(kk >> 32);
            uint32_t idx = 0xFFFFFFFFu - (uint32_t)(kk & 0xFFFFFFFFull);
            probs_out[b * KK + rank] = __uint_as_float(bits);
            cxy[(b * KK + rank) * 2]     = (float)(idx % WW);
            cxy[(b * KK + rank) * 2 + 1] = (float)(idx / WW);
        }
    }
}

// ---------------------------------------- closest-center argmin + counts hist
__global__ void __launch_bounds__(256) k_assign(const float* __restrict__ reg,
                                                const float* __restrict__ cxy,
                                                const float* __restrict__ segsf,
                                                float* __restrict__ closest_out,
                                                uint32_t* __restrict__ counts) {
    __shared__ float2 cc[KK];
    int p0 = blockIdx.x * 256;
    int b = p0 / HWW;
    int tid = threadIdx.x;
    if (tid < KK) cc[tid] = ((const float2*)cxy)[b * KK + tid];
    __syncthreads();
    int p = p0 + tid;
    int r = p - b * HWW;
    int h = r / WW, w = r - h * WW;
    float rx = reg[(size_t)b * 2 * HWW + r];
    float ry = reg[(size_t)b * 2 * HWW + HWW + r];
    float px = (float)(w + 1) - rx;
    float py = (float)(h + 1) - ry;
    float best = __builtin_inff();
    int bk = 0;
#pragma unroll 4
    for (int k = 0; k < KK; ++k) {
        float2 c = cc[k];
        float dx = __fsub_rn(px, c.x);
        float dy = __fsub_rn(py, c.y);
        float d2 = __fadd_rn(__fmul_rn(dx, dx), __fmul_rn(dy, dy));  // no fma, match ref
        if (d2 < best) { best = d2; bk = k; }   // strict < : first-occurrence argmin
    }
    closest_out[p] = (float)(bk + 1);
    int seg = (int)segsf[p];
    if (seg >= 24 && seg <= 33) {
        atomicAdd(&counts[(b * (KK + 1) + (bk + 1)) * NC + seg], 1u);
    }
}

// ---------------------------------------- per-instance majority class, n, valid
__global__ void __launch_bounds__(256) k_inst(const uint32_t* __restrict__ counts,
                                              const float* __restrict__ probs_out,
                                              float* __restrict__ ic_out,
                                              float* __restrict__ np_out,
                                              float* __restrict__ va_out) {
    int t = blockIdx.x * 256 + threadIdx.x;
    if (t >= NB * KK) return;
    int b = t / KK, k = t - b * KK;
    const uint32_t* row = counts + (size_t)(b * (KK + 1) + (k + 1)) * NC;
    uint32_t n = 0, mx = 0;
    int am = 0;
#pragma unroll
    for (int c = 0; c < NC; ++c) {
        uint32_t x = row[c];
        n += x;
        if (x > mx) { mx = x; am = c; }   // first-occurrence argmax
    }
    ic_out[t] = (float)am;
    np_out[t] = (float)n;
    va_out[t] = (n > 0u && probs_out[t] > 0.f) ? 1.f : 0.f;
}

// ---------------------------------------- per-instance softmax-prob sums
template <int USE_STATS>
__global__ void __launch_bounds__(256) k_sums(const float* __restrict__ logits,
                                              const float* __restrict__ segsf,
                                              const float* __restrict__ closestf,
                                              const float* __restrict__ icf,
                                              const float* __restrict__ smax,
                                              const float* __restrict__ sden,
                                              float* __restrict__ sums) {
    __shared__ int ic_l[KK];
    __shared__ float psum[KK + 1];
    int tid = threadIdx.x;
    int p0 = blockIdx.x * 256;
    int b = p0 / HWW;
    if (tid < KK) ic_l[tid] = (int)icf[b * KK + tid];
    if (tid < KK + 1) psum[tid] = 0.f;
    __syncthreads();
    int p = p0 + tid;
    int r = p - b * HWW;
    int seg = (int)segsf[p];
    if (seg >= 24 && seg <= 33) {
        int cl = (int)closestf[p];
        int ic = ic_l[cl - 1];
        const float* base = logits + (size_t)b * NC * HWW + r;
        float pr;
        if (USE_STATS) {
            float vmax = smax[p], den = sden[p];
            float lv = base[(size_t)ic * HWW];
            pr = __expf(lv - vmax) / den;
        } else {
            float v[NC];
            float vmax = -3e38f, lv = 0.f;
#pragma unroll
            for (int c = 0; c < NC; ++c) {
                v[c] = base[(size_t)c * HWW];
                vmax = fmaxf(vmax, v[c]);
                if (c == ic) lv = v[c];
            }
            float s = 0.f;
#pragma unroll
            for (int c = 0; c < NC; ++c) s += __expf(v[c] - vmax);
            pr = __expf(lv - vmax) / s;
        }
        atomicAdd(&psum[cl], pr);
    }
    __syncthreads();
    if (tid < KK + 1) {
        float x = psum[tid];
        if (x != 0.f) atomicAdd(&sums[b * (KK + 1) + tid], x);
    }
}

// ---------------------------------------- final seg_prob
__global__ void __launch_bounds__(256) k_segprob(const float* __restrict__ sums,
                                                 const float* __restrict__ np_out,
                                                 float* __restrict__ sp_out) {
    int t = blockIdx.x * 256 + threadIdx.x;
    if (t >= NB * KK) return;
    int b = t / KK, k = t - b * KK;
    float n = np_out[t];
    float s = sums[b * (KK + 1) + k + 1];
    sp_out[t] = (n > 0.f) ? (s / n) : 0.f;
}

extern "C" void kernel_launch(void* const* d_in, const int* in_sizes, int n_in,
                              void* d_out, int out_size, void* d_ws, size_t ws_size,
                              hipStream_t stream) {
    const float* logits = (const float*)d_in[0];
    const float* cmap   = (const float*)d_in[1];
    const float* reg    = (const float*)d_in[2];
    float* out = (float*)d_out;
    float* o_ic   = out;
    float* o_prob = out + NB * KK;
    float* o_sp   = out + 2 * NB * KK;
    float* o_np   = out + 3 * NB * KK;
    float* o_va   = out + 4 * NB * KK;
    float* o_segs = out + 5 * NB * KK;
    float* o_clo  = out + 5 * NB * KK + NB * HWW;

    char* w = (char*)d_ws;
    size_t off = 0;
    auto alloc = [&](size_t bytes) {
        off = (off + 15) & ~((size_t)15);
        void* p = w + off;
        off += bytes;
        return p;
    };
    uint64_t* cand   = (uint64_t*)alloc(sizeof(uint64_t) * NB * CAP);
    uint32_t* cnt    = (uint32_t*)alloc(sizeof(uint32_t) * NB);
    uint32_t* counts = (uint32_t*)alloc(sizeof(uint32_t) * NB * (KK + 1) * NC);
    float* sums      = (float*)alloc(sizeof(float) * NB * (KK + 1));
    float* cxy       = (float*)alloc(sizeof(float) * NB * KK * 2);
    size_t base_need = (off + 15) & ~((size_t)15);
    float* smax = (float*)(w + base_need);
    float* sden = smax + (size_t)NB * HWW;
    int use_stats = (base_need + sizeof(float) * 2 * (size_t)NB * HWW) <= ws_size ? 1 : 0;

    k_init<<<(NB * (KK + 1) * NC + 255) / 256, 256, 0, stream>>>(cnt, counts, sums);
    k_seg<<<NB * HWW / 2 / 256, 256, 0, stream>>>(logits, o_segs, smax, sden, use_stats);
    k_nms<<<NB * (HH / TH) * (WW / TW), 256, 0, stream>>>(cmap, cand, cnt);
    k_topk<<<NB, 1024, 0, stream>>>(cand, cnt, o_prob, cxy);
    k_assign<<<NB * HWW / 256, 256, 0, stream>>>(reg, cxy, o_segs, o_clo, counts);
    k_inst<<<(NB * KK + 255) / 256, 256, 0, stream>>>(counts, o_prob, o_ic, o_np, o_va);
    if (use_stats)
        k_sums<1><<<NB * HWW / 256, 256, 0, stream>>>(logits, o_segs, o_clo, o_ic, smax, sden, sums);
    else
        k_sums<0><<<NB * HWW / 256, 256, 0, stream>>>(logits, o_segs, o_clo, o_ic, smax, sden, sums);
    k_segprob<<<(NB * KK + 255) / 256, 256, 0, stream>>>(sums, o_np, o_sp);
}

// Round 6
// 160.907 us; speedup vs baseline: 1.4327x; 1.4327x over previous
//
#include <hip/hip_runtime.h>
#include <stdint.h>

#define NB 2
#define NC 34
#define HH 512
#define WW 1024
#define HWW (HH*WW)
#define KK 200
#define CAP 32768
#define MCAP 4096
#define LCAP 512
#define VBIN 4096

// NMS tiling
#define TW 128
#define TH 16
#define HALO 3

// ---------------------------------------------------------------- init ws
__global__ void __launch_bounds__(256) k_init(uint32_t* cnt, uint32_t* counts, float* sums) {
    int t = blockIdx.x * 256 + threadIdx.x;
    if (t < NB) cnt[t] = 0u;
    if (t < NB * (KK + 1) * NC) counts[t] = 0u;
    if (t < NB * (KK + 1)) sums[t] = 0.f;
}

// ------------------------------------------- per-pixel argmax + softmax stats
__global__ void __launch_bounds__(256) k_seg(const float* __restrict__ logits,
                                             float* __restrict__ segs_out,
                                             float* __restrict__ smax,
                                             float* __restrict__ sden,
                                             int use_stats) {
    int t = blockIdx.x * 256 + threadIdx.x;   // t < NB*HWW/2
    if (t >= NB * HWW / 2) return;
    int p = t * 2;
    int b = p / HWW, r = p - b * HWW;
    const float* base = logits + (size_t)b * NC * HWW + r;
    float2 v[NC];
    float m0 = -3e38f, m1 = -3e38f;
    int a0 = 0, a1 = 0;
#pragma unroll
    for (int c = 0; c < NC; ++c) {
        v[c] = *(const float2*)(base + (size_t)c * HWW);
        if (v[c].x > m0) { m0 = v[c].x; a0 = c; }
        if (v[c].y > m1) { m1 = v[c].y; a1 = c; }
    }
    float s0 = 0.f, s1 = 0.f;
#pragma unroll
    for (int c = 0; c < NC; ++c) {
        s0 += __expf(v[c].x - m0);
        s1 += __expf(v[c].y - m1);
    }
    *(float2*)(segs_out + p) = make_float2((float)a0, (float)a1);
    if (use_stats) {
        *(float2*)(smax + p) = make_float2(m0, m1);
        *(float2*)(sden + p) = make_float2(s0, s1);
    }
}

// ----------------- NMS: separable 7x7 max via LDS + per-block candidate compaction
__global__ void __launch_bounds__(256) k_nms(const float* __restrict__ cmap,
                                             uint64_t* __restrict__ cand,
                                             uint32_t* __restrict__ cnt) {
    __shared__ float sIn[TH + 2 * HALO][TW + 2 * HALO];   // 22 x 134
    __shared__ float sH[TH + 2 * HALO][TW];               // 22 x 128
    __shared__ uint64_t lc[LCAP];
    __shared__ uint32_t lcnt, gbase;
    int t = blockIdx.x;
    int bx = t & (WW / TW - 1);          // 0..7
    int by = (t >> 3) & (HH / TH - 1);   // 0..31
    int b = t >> 8;                      // 0..NB-1
    int tid = threadIdx.x;
    const float* bb = cmap + (size_t)b * HWW;
    if (tid == 0) lcnt = 0u;

    const int LW = TW + 2 * HALO;                 // 134
    const int LH = TH + 2 * HALO;                 // 22
    for (int idx = tid; idx < LW * LH; idx += 256) {
        int r = idx / LW, c = idx - r * LW;
        int gh = by * TH + r - HALO;
        int gw = bx * TW + c - HALO;
        float v = -3e38f;
        if (gh >= 0 && gh < HH && gw >= 0 && gw < WW) v = bb[gh * WW + gw];
        sIn[r][c] = v;
    }
    __syncthreads();

    // horizontal 1x7 max
    for (int idx = tid; idx < LH * TW; idx += 256) {
        int r = idx / TW, c = idx - r * TW;
        float m = fmaxf(fmaxf(fmaxf(sIn[r][c], sIn[r][c + 1]),
                              fmaxf(sIn[r][c + 2], sIn[r][c + 3])),
                        fmaxf(fmaxf(sIn[r][c + 4], sIn[r][c + 5]), sIn[r][c + 6]));
        sH[r][c] = m;
    }
    __syncthreads();

    // vertical 7x1 max + candidate test -> LDS compaction
    for (int idx = tid; idx < TH * TW; idx += 256) {
        int r = idx >> 7, c = idx & (TW - 1);
        float cv = sIn[r + HALO][c + HALO];
        float m = fmaxf(fmaxf(fmaxf(sH[r][c], sH[r + 1][c]),
                              fmaxf(sH[r + 2][c], sH[r + 3][c])),
                        fmaxf(fmaxf(sH[r + 4][c], sH[r + 5][c]), sH[r + 6][c]));
        if (m > 0.1f && cv == m) {
            int gh = by * TH + r;
            int gw = bx * TW + c;
            uint32_t rr = (uint32_t)(gh * WW + gw);
            uint32_t pos = atomicAdd(&lcnt, 1u);   // LDS atomic: per-CU, fast
            if (pos < LCAP)
                lc[pos] = ((uint64_t)__float_as_uint(cv) << 32) |
                          (uint64_t)(0xFFFFFFFFu - rr);
        }
    }
    __syncthreads();
    uint32_t n = lcnt;
    if (n > LCAP) n = LCAP;
    if (tid == 0 && n) gbase = atomicAdd(&cnt[b], n);   // ONE global atomic per block
    __syncthreads();
    for (uint32_t i = tid; i < n; i += 256) {
        uint32_t pos = gbase + i;
        if (pos < CAP) cand[(size_t)b * CAP + pos] = lc[i];
    }
}

// ---- exact top-K: value-binned histogram (1 pass) + parallel suffix scan + rank
__global__ void __launch_bounds__(1024) k_topk(const uint64_t* __restrict__ cand,
                                               const uint32_t* __restrict__ cnt,
                                               float* __restrict__ probs_out,
                                               float* __restrict__ cxy) {
    int b = blockIdx.x;
    int tid = threadIdx.x;
    __shared__ uint32_t hist[VBIN];       // 16 KB
    __shared__ uint32_t part[1024];       // 4 KB
    __shared__ uint64_t lkey[MCAP];       // 32 KB
    __shared__ uint32_t lM;
    __shared__ int sBstar;

    if (tid < KK) {
        probs_out[b * KK + tid] = 0.f;
        cxy[(b * KK + tid) * 2]     = 1e19f;  // invalid -> huge coords -> inf dist
        cxy[(b * KK + tid) * 2 + 1] = 1e19f;
    }
    if (tid == 0) { lM = 0u; sBstar = 0; }
    for (int i = tid; i < VBIN; i += 1024) hist[i] = 0u;
    uint32_t N = cnt[b];
    if (N > CAP) N = CAP;
    const uint64_t* cb = cand + (size_t)b * CAP;
    __syncthreads();

    if (N > KK) {
        // one histogram pass over N; bin = (int)(v*VBIN) is monotone in v and
        // well-spread for NMS-survivor values (maxima of 49 samples pile near 1)
        for (uint32_t i = tid; i < N; i += 1024) {
            float v = __uint_as_float((uint32_t)(cb[i] >> 32));
            int bin = (int)(v * (float)VBIN);
            bin = bin < 0 ? 0 : (bin > VBIN - 1 ? VBIN - 1 : bin);
            atomicAdd(&hist[bin], 1u);
        }
        __syncthreads();
        // descending-chunk sums: thread t covers bins [VBIN-4(t+1), VBIN-4t)
        int base = VBIN - 4 * (tid + 1);
        uint32_t s = hist[base] + hist[base + 1] + hist[base + 2] + hist[base + 3];
        part[tid] = s;
        __syncthreads();
        // Hillis-Steele inclusive scan: part[t] = sum of chunks 0..t (suffix from top)
        for (int off = 1; off < 1024; off <<= 1) {
            uint32_t add = (tid >= off) ? part[tid - off] : 0u;
            __syncthreads();
            part[tid] += add;
            __syncthreads();
        }
        // smallest t with P_t >= KK -> walk its 4 bins (descending) for exact b*
        {
            uint32_t Pt = part[tid];
            uint32_t Pp = (tid > 0) ? part[tid - 1] : 0u;
            if (Pt >= KK && Pp < KK) {
                uint32_t cum = Pp;
                int bs = base;
                for (int j = base + 3; j >= base; --j) {
                    cum += hist[j];
                    if (cum >= KK) { bs = j; break; }
                }
                sBstar = bs;
            }
        }
        __syncthreads();
    }
    int bstar = sBstar;   // 0 if N<=KK (collect everything)

    // collect all candidates with bin >= bstar  (M = KK + same-bin extras, small)
    for (uint32_t i = tid; i < N; i += 1024) {
        uint64_t kk = cb[i];
        float v = __uint_as_float((uint32_t)(kk >> 32));
        int bin = (int)(v * (float)VBIN);
        bin = bin < 0 ? 0 : (bin > VBIN - 1 ? VBIN - 1 : bin);
        if (bin >= bstar) {
            uint32_t pos = atomicAdd(&lM, 1u);
            if (pos < MCAP) lkey[pos] = kk;
        }
    }
    __syncthreads();
    uint32_t M = lM;
    if (M > MCAP) M = MCAP;
    // exact global rank (desc value, asc index via ~idx in low bits)
    for (uint32_t i = tid; i < M; i += 1024) {
        uint64_t kk = lkey[i];
        uint32_t rank = 0;
        for (uint32_t j = 0; j < M; ++j) rank += (lkey[j] > kk) ? 1u : 0u;
        if (rank < KK) {
            uint32_t bits = (uint32_t)(kk >> 32);
            uint32_t idx = 0xFFFFFFFFu - (uint32_t)(kk & 0xFFFFFFFFull);
            probs_out[b * KK + rank] = __uint_as_float(bits);
            cxy[(b * KK + rank) * 2]     = (float)(idx % WW);
            cxy[(b * KK + rank) * 2 + 1] = (float)(idx / WW);
        }
    }
}

// ---------------------------------------- closest-center argmin + counts hist
__global__ void __launch_bounds__(256) k_assign(const float* __restrict__ reg,
                                                const float* __restrict__ cxy,
                                                const float* __restrict__ segsf,
                                                float* __restrict__ closest_out,
                                                uint32_t* __restrict__ counts) {
    __shared__ float2 cc[KK];
    int p0 = blockIdx.x * 256;
    int b = p0 / HWW;
    int tid = threadIdx.x;
    if (tid < KK) cc[tid] = ((const float2*)cxy)[b * KK + tid];
    __syncthreads();
    int p = p0 + tid;
    int r = p - b * HWW;
    int h = r / WW, w = r - h * WW;
    float rx = reg[(size_t)b * 2 * HWW + r];
    float ry = reg[(size_t)b * 2 * HWW + HWW + r];
    float px = (float)(w + 1) - rx;
    float py = (float)(h + 1) - ry;
    float best = __builtin_inff();
    int bk = 0;
#pragma unroll 4
    for (int k = 0; k < KK; ++k) {
        float2 c = cc[k];
        float dx = __fsub_rn(px, c.x);
        float dy = __fsub_rn(py, c.y);
        float d2 = __fadd_rn(__fmul_rn(dx, dx), __fmul_rn(dy, dy));  // no fma, match ref
        if (d2 < best) { best = d2; bk = k; }   // strict < : first-occurrence argmin
    }
    closest_out[p] = (float)(bk + 1);
    int seg = (int)segsf[p];
    if (seg >= 24 && seg <= 33) {
        atomicAdd(&counts[(b * (KK + 1) + (bk + 1)) * NC + seg], 1u);
    }
}

// ---------------------------------------- per-instance majority class, n, valid
__global__ void __launch_bounds__(256) k_inst(const uint32_t* __restrict__ counts,
                                              const float* __restrict__ probs_out,
                                              float* __restrict__ ic_out,
                                              float* __restrict__ np_out,
                                              float* __restrict__ va_out) {
    int t = blockIdx.x * 256 + threadIdx.x;
    if (t >= NB * KK) return;
    int b = t / KK, k = t - b * KK;
    const uint32_t* row = counts + (size_t)(b * (KK + 1) + (k + 1)) * NC;
    uint32_t n = 0, mx = 0;
    int am = 0;
#pragma unroll
    for (int c = 0; c < NC; ++c) {
        uint32_t x = row[c];
        n += x;
        if (x > mx) { mx = x; am = c; }   // first-occurrence argmax
    }
    ic_out[t] = (float)am;
    np_out[t] = (float)n;
    va_out[t] = (n > 0u && probs_out[t] > 0.f) ? 1.f : 0.f;
}

// ---------------------------------------- per-instance softmax-prob sums
template <int USE_STATS>
__global__ void __launch_bounds__(256) k_sums(const float* __restrict__ logits,
                                              const float* __restrict__ segsf,
                                              const float* __restrict__ closestf,
                                              const float* __restrict__ icf,
                                              const float* __restrict__ smax,
                                              const float* __restrict__ sden,
                                              float* __restrict__ sums) {
    __shared__ int ic_l[KK];
    __shared__ float psum[KK + 1];
    int tid = threadIdx.x;
    int p0 = blockIdx.x * 256;
    int b = p0 / HWW;
    if (tid < KK) ic_l[tid] = (int)icf[b * KK + tid];
    if (tid < KK + 1) psum[tid] = 0.f;
    __syncthreads();
    int p = p0 + tid;
    int r = p - b * HWW;
    int seg = (int)segsf[p];
    if (seg >= 24 && seg <= 33) {
        int cl = (int)closestf[p];
        int ic = ic_l[cl - 1];
        const float* base = logits + (size_t)b * NC * HWW + r;
        float pr;
        if (USE_STATS) {
            float vmax = smax[p], den = sden[p];
            float lv = base[(size_t)ic * HWW];
            pr = __expf(lv - vmax) / den;
        } else {
            float v[NC];
            float vmax = -3e38f, lv = 0.f;
#pragma unroll
            for (int c = 0; c < NC; ++c) {
                v[c] = base[(size_t)c * HWW];
                vmax = fmaxf(vmax, v[c]);
                if (c == ic) lv = v[c];
            }
            float s = 0.f;
#pragma unroll
            for (int c = 0; c < NC; ++c) s += __expf(v[c] - vmax);
            pr = __expf(lv - vmax) / s;
        }
        atomicAdd(&psum[cl], pr);
    }
    __syncthreads();
    if (tid < KK + 1) {
        float x = psum[tid];
        if (x != 0.f) atomicAdd(&sums[b * (KK + 1) + tid], x);
    }
}

// ---------------------------------------- final seg_prob
__global__ void __launch_bounds__(256) k_segprob(const float* __restrict__ sums,
                                                 const float* __restrict__ np_out,
                                                 float* __restrict__ sp_out) {
    int t = blockIdx.x * 256 + threadIdx.x;
    if (t >= NB * KK) return;
    int b = t / KK, k = t - b * KK;
    float n = np_out[t];
    float s = sums[b * (KK + 1) + k + 1];
    sp_out[t] = (n > 0.f) ? (s / n) : 0.f;
}

extern "C" void kernel_launch(void* const* d_in, const int* in_sizes, int n_in,
                              void* d_out, int out_size, void* d_ws, size_t ws_size,
                              hipStream_t stream) {
    const float* logits = (const float*)d_in[0];
    const float* cmap   = (const float*)d_in[1];
    const float* reg    = (const float*)d_in[2];
    float* out = (float*)d_out;
    float* o_ic   = out;
    float* o_prob = out + NB * KK;
    float* o_sp   = out + 2 * NB * KK;
    float* o_np   = out + 3 * NB * KK;
    float* o_va   = out + 4 * NB * KK;
    float* o_segs = out + 5 * NB * KK;
    float* o_clo  = out + 5 * NB * KK + NB * HWW;

    char* w = (char*)d_ws;
    size_t off = 0;
    auto alloc = [&](size_t bytes) {
        off = (off + 15) & ~((size_t)15);
        void* p = w + off;
        off += bytes;
        return p;
    };
    uint64_t* cand   = (uint64_t*)alloc(sizeof(uint64_t) * NB * CAP);
    uint32_t* cnt    = (uint32_t*)alloc(sizeof(uint32_t) * NB);
    uint32_t* counts = (uint32_t*)alloc(sizeof(uint32_t) * NB * (KK + 1) * NC);
    float* sums      = (float*)alloc(sizeof(float) * NB * (KK + 1));
    float* cxy       = (float*)alloc(sizeof(float) * NB * KK * 2);
    size_t base_need = (off + 15) & ~((size_t)15);
    float* smax = (float*)(w + base_need);
    float* sden = smax + (size_t)NB * HWW;
    int use_stats = (base_need + sizeof(float) * 2 * (size_t)NB * HWW) <= ws_size ? 1 : 0;

    k_init<<<(NB * (KK + 1) * NC + 255) / 256, 256, 0, stream>>>(cnt, counts, sums);
    k_seg<<<NB * HWW / 2 / 256, 256, 0, stream>>>(logits, o_segs, smax, sden, use_stats);
    k_nms<<<NB * (HH / TH) * (WW / TW), 256, 0, stream>>>(cmap, cand, cnt);
    k_topk<<<NB, 1024, 0, stream>>>(cand, cnt, o_prob, cxy);
    k_assign<<<NB * HWW / 256, 256, 0, stream>>>(reg, cxy, o_segs, o_clo, counts);
    k_inst<<<(NB * KK + 255) / 256, 256, 0, stream>>>(counts, o_prob, o_ic, o_np, o_va);
    if (use_stats)
        k_sums<1><<<NB * HWW / 256, 256, 0, stream>>>(logits, o_segs, o_clo, o_ic, smax, sden, sums);
    else
        k_sums<0><<<NB * HWW / 256, 256, 0, stream>>>(logits, o_segs, o_clo, o_ic, smax, sden, sums);
    k_segprob<<<(NB * KK + 255) / 256, 256, 0, stream>>>(sums, o_np, o_sp);
}

// Round 7
// 128.859 us; speedup vs baseline: 1.7890x; 1.2487x over previous
//
#include <hip/hip_runtime.h>
#include <stdint.h>

#define NB 2
#define NC 34
#define HH 512
#define WW 1024
#define HWW (HH*WW)
#define KK 200
#define CAP 32768
#define MCAP 4096
#define LCAP 512
#define VBIN 4096

// NMS tiling
#define TW 128
#define TH 16
#define HALO 3

// ------------------- per-pixel argmax + fused softmax stat (+ ws init, block 0)
__global__ void __launch_bounds__(256) k_seg(const float* __restrict__ logits,
                                             float* __restrict__ segs_out,
                                             float* __restrict__ scomb,
                                             uint32_t* __restrict__ cnt,
                                             uint32_t* __restrict__ counts,
                                             float* __restrict__ sums,
                                             int use_stats) {
    int tid = threadIdx.x;
    if (blockIdx.x == 0) {   // fold former k_init here (consumers are later kernels)
        for (int i = tid; i < NB * (KK + 1) * NC; i += 256) counts[i] = 0u;
        for (int i = tid; i < NB * (KK + 1); i += 256) sums[i] = 0.f;
        if (tid < NB) cnt[tid] = 0u;
    }
    int t = blockIdx.x * 256 + tid;   // t < NB*HWW/2
    if (t >= NB * HWW / 2) return;
    int p = t * 2;
    int b = p / HWW, r = p - b * HWW;
    const float* base = logits + (size_t)b * NC * HWW + r;
    float2 v[NC];
    float m0 = -3e38f, m1 = -3e38f;
    int a0 = 0, a1 = 0;
#pragma unroll
    for (int c = 0; c < NC; ++c) {
        v[c] = *(const float2*)(base + (size_t)c * HWW);
        if (v[c].x > m0) { m0 = v[c].x; a0 = c; }
        if (v[c].y > m1) { m1 = v[c].y; a1 = c; }
    }
    float s0 = 0.f, s1 = 0.f;
#pragma unroll
    for (int c = 0; c < NC; ++c) {
        s0 += __expf(v[c].x - m0);
        s1 += __expf(v[c].y - m1);
    }
    *(float2*)(segs_out + p) = make_float2((float)a0, (float)a1);
    if (use_stats) {
        // pr(class) = exp(logit - (max + log(den)))
        *(float2*)(scomb + p) = make_float2(m0 + __logf(s0), m1 + __logf(s1));
    }
}

// ----------------- NMS: separable 7x7 max via LDS + per-block candidate compaction
__global__ void __launch_bounds__(256) k_nms(const float* __restrict__ cmap,
                                             uint64_t* __restrict__ cand,
                                             uint32_t* __restrict__ cnt) {
    __shared__ float sIn[TH + 2 * HALO][TW + 2 * HALO];   // 22 x 134
    __shared__ float sH[TH + 2 * HALO][TW];               // 22 x 128
    __shared__ uint64_t lc[LCAP];
    __shared__ uint32_t lcnt, gbase;
    int t = blockIdx.x;
    int bx = t & (WW / TW - 1);          // 0..7
    int by = (t >> 3) & (HH / TH - 1);   // 0..31
    int b = t >> 8;                      // 0..NB-1
    int tid = threadIdx.x;
    const float* bb = cmap + (size_t)b * HWW;
    if (tid == 0) lcnt = 0u;

    const int LW = TW + 2 * HALO;                 // 134
    const int LH = TH + 2 * HALO;                 // 22
    for (int idx = tid; idx < LW * LH; idx += 256) {
        int r = idx / LW, c = idx - r * LW;
        int gh = by * TH + r - HALO;
        int gw = bx * TW + c - HALO;
        float v = -3e38f;
        if (gh >= 0 && gh < HH && gw >= 0 && gw < WW) v = bb[gh * WW + gw];
        sIn[r][c] = v;
    }
    __syncthreads();

    for (int idx = tid; idx < LH * TW; idx += 256) {
        int r = idx / TW, c = idx - r * TW;
        float m = fmaxf(fmaxf(fmaxf(sIn[r][c], sIn[r][c + 1]),
                              fmaxf(sIn[r][c + 2], sIn[r][c + 3])),
                        fmaxf(fmaxf(sIn[r][c + 4], sIn[r][c + 5]), sIn[r][c + 6]));
        sH[r][c] = m;
    }
    __syncthreads();

    for (int idx = tid; idx < TH * TW; idx += 256) {
        int r = idx >> 7, c = idx & (TW - 1);
        float cv = sIn[r + HALO][c + HALO];
        float m = fmaxf(fmaxf(fmaxf(sH[r][c], sH[r + 1][c]),
                              fmaxf(sH[r + 2][c], sH[r + 3][c])),
                        fmaxf(fmaxf(sH[r + 4][c], sH[r + 5][c]), sH[r + 6][c]));
        if (m > 0.1f && cv == m) {
            int gh = by * TH + r;
            int gw = bx * TW + c;
            uint32_t rr = (uint32_t)(gh * WW + gw);
            uint32_t pos = atomicAdd(&lcnt, 1u);
            if (pos < LCAP)
                lc[pos] = ((uint64_t)__float_as_uint(cv) << 32) |
                          (uint64_t)(0xFFFFFFFFu - rr);
        }
    }
    __syncthreads();
    uint32_t n = lcnt;
    if (n > LCAP) n = LCAP;
    if (tid == 0 && n) gbase = atomicAdd(&cnt[b], n);
    __syncthreads();
    for (uint32_t i = tid; i < n; i += 256) {
        uint32_t pos = gbase + i;
        if (pos < CAP) cand[(size_t)b * CAP + pos] = lc[i];
    }
}

// ---- exact top-K: value-binned histogram (1 pass) + parallel suffix scan + rank
__global__ void __launch_bounds__(1024) k_topk(const uint64_t* __restrict__ cand,
                                               const uint32_t* __restrict__ cnt,
                                               float* __restrict__ probs_out,
                                               float* __restrict__ cxy) {
    int b = blockIdx.x;
    int tid = threadIdx.x;
    __shared__ uint32_t hist[VBIN];
    __shared__ uint32_t part[1024];
    __shared__ uint64_t lkey[MCAP];
    __shared__ uint32_t lM;
    __shared__ int sBstar;

    if (tid < KK) {
        probs_out[b * KK + tid] = 0.f;
        cxy[(b * KK + tid) * 2]     = 1e19f;
        cxy[(b * KK + tid) * 2 + 1] = 1e19f;
    }
    if (tid == 0) { lM = 0u; sBstar = 0; }
    for (int i = tid; i < VBIN; i += 1024) hist[i] = 0u;
    uint32_t N = cnt[b];
    if (N > CAP) N = CAP;
    const uint64_t* cb = cand + (size_t)b * CAP;
    __syncthreads();

    if (N > KK) {
        for (uint32_t i = tid; i < N; i += 1024) {
            float v = __uint_as_float((uint32_t)(cb[i] >> 32));
            int bin = (int)(v * (float)VBIN);
            bin = bin < 0 ? 0 : (bin > VBIN - 1 ? VBIN - 1 : bin);
            atomicAdd(&hist[bin], 1u);
        }
        __syncthreads();
        int base = VBIN - 4 * (tid + 1);
        uint32_t s = hist[base] + hist[base + 1] + hist[base + 2] + hist[base + 3];
        part[tid] = s;
        __syncthreads();
        for (int off = 1; off < 1024; off <<= 1) {
            uint32_t add = (tid >= off) ? part[tid - off] : 0u;
            __syncthreads();
            part[tid] += add;
            __syncthreads();
        }
        {
            uint32_t Pt = part[tid];
            uint32_t Pp = (tid > 0) ? part[tid - 1] : 0u;
            if (Pt >= KK && Pp < KK) {
                uint32_t cum = Pp;
                int bs = base;
                for (int j = base + 3; j >= base; --j) {
                    cum += hist[j];
                    if (cum >= KK) { bs = j; break; }
                }
                sBstar = bs;
            }
        }
        __syncthreads();
    }
    int bstar = sBstar;

    for (uint32_t i = tid; i < N; i += 1024) {
        uint64_t kk = cb[i];
        float v = __uint_as_float((uint32_t)(kk >> 32));
        int bin = (int)(v * (float)VBIN);
        bin = bin < 0 ? 0 : (bin > VBIN - 1 ? VBIN - 1 : bin);
        if (bin >= bstar) {
            uint32_t pos = atomicAdd(&lM, 1u);
            if (pos < MCAP) lkey[pos] = kk;
        }
    }
    __syncthreads();
    uint32_t M = lM;
    if (M > MCAP) M = MCAP;
    for (uint32_t i = tid; i < M; i += 1024) {
        uint64_t kk = lkey[i];
        uint32_t rank = 0;
        for (uint32_t j = 0; j < M; ++j) rank += (lkey[j] > kk) ? 1u : 0u;
        if (rank < KK) {
            uint32_t bits = (uint32_t)(kk >> 32);
            uint32_t idx = 0xFFFFFFFFu - (uint32_t)(kk & 0xFFFFFFFFull);
            probs_out[b * KK + rank] = __uint_as_float(bits);
            cxy[(b * KK + rank) * 2]     = (float)(idx % WW);
            cxy[(b * KK + rank) * 2 + 1] = (float)(idx / WW);
        }
    }
}

// ------------- closest-center argmin with EXACT per-tile pruning + counts hist
// A center is dropped only if min_dist(c,box) > min_k max_dist(k,box) + 1.0,
// which guarantees (incl. fp rounding, margin ~2*tau) it can never be the fp32
// argmin nor tie it. Shortlist keeps ascending-k order -> identical tie-breaks.
__global__ void __launch_bounds__(256) k_assign(const float* __restrict__ reg,
                                                const float* __restrict__ cxy,
                                                const float* __restrict__ segsf,
                                                float* __restrict__ closest_out,
                                                uint32_t* __restrict__ counts) {
    __shared__ float2 cc[KK];
    __shared__ float4 ccs[KK];
    __shared__ float sred[4][4];   // [quantity][wave]
    __shared__ uint32_t wcnt[4];
    __shared__ float stau2;
    __shared__ uint32_t sS;

    int t = blockIdx.x;
    int tx = t & 63;              // 64 tiles across
    int ty = (t >> 6) & 31;       // 32 tiles down
    int b = t >> 11;
    int tid = threadIdx.x;
    int lane = tid & 63, wv = tid >> 6;
    int w = tx * 16 + (tid & 15);
    int h = ty * 16 + (tid >> 4);
    int r = h * WW + w;
    int p = b * HWW + r;

    if (tid < KK) cc[tid] = ((const float2*)cxy)[b * KK + tid];
    __syncthreads();

    float rx = reg[(size_t)b * 2 * HWW + r];
    float ry = reg[(size_t)b * 2 * HWW + HWW + r];
    float px = (float)(w + 1) - rx;
    float py = (float)(h + 1) - ry;

    // block bounding box of (px,py) via wave shuffles + LDS
    float mnx = px, mxx = px, mny = py, mxy = py;
#pragma unroll
    for (int off = 1; off < 64; off <<= 1) {
        mnx = fminf(mnx, __shfl_xor(mnx, off, 64));
        mxx = fmaxf(mxx, __shfl_xor(mxx, off, 64));
        mny = fminf(mny, __shfl_xor(mny, off, 64));
        mxy = fmaxf(mxy, __shfl_xor(mxy, off, 64));
    }
    if (lane == 0) { sred[0][wv] = mnx; sred[1][wv] = mxx; sred[2][wv] = mny; sred[3][wv] = mxy; }
    __syncthreads();
    float xmin = fminf(fminf(sred[0][0], sred[0][1]), fminf(sred[0][2], sred[0][3]));
    float xmax = fmaxf(fmaxf(sred[1][0], sred[1][1]), fmaxf(sred[1][2], sred[1][3]));
    float ymin = fminf(fminf(sred[2][0], sred[2][1]), fminf(sred[2][2], sred[2][3]));
    float ymax = fmaxf(fmaxf(sred[3][0], sred[3][1]), fmaxf(sred[3][2], sred[3][3]));

    // per-center min/max distance-to-box bounds
    float2 c0 = cc[tid < KK ? tid : 0];
    float mdx = fmaxf(fmaxf(xmin - c0.x, c0.x - xmax), 0.f);
    float mdy = fmaxf(fmaxf(ymin - c0.y, c0.y - ymax), 0.f);
    float mind2 = mdx * mdx + mdy * mdy;
    float Mdx = fmaxf(c0.x - xmin, xmax - c0.x);
    float Mdy = fmaxf(c0.y - ymin, ymax - c0.y);
    float maxd2 = Mdx * Mdx + Mdy * Mdy;

    float v = (tid < KK) ? maxd2 : 3.0e38f;
#pragma unroll
    for (int off = 1; off < 64; off <<= 1) v = fminf(v, __shfl_xor(v, off, 64));
    if (lane == 0) sred[0][wv] = v;
    __syncthreads();
    if (tid == 0) {
        float mm = fminf(fminf(sred[0][0], sred[0][1]), fminf(sred[0][2], sred[0][3]));
        float tau = __builtin_sqrtf(mm) + 1.0f;
        stau2 = tau * tau;
    }
    __syncthreads();

    // ordered compaction of surviving centers
    bool flag = (tid < KK) && (mind2 <= stau2);
    uint64_t mask = __ballot(flag);
    uint32_t myoff = (uint32_t)__popcll(mask & ((1ull << lane) - 1ull));
    if (lane == 0) wcnt[wv] = (uint32_t)__popcll(mask);
    __syncthreads();
    uint32_t pre = 0;
    for (int i = 0; i < wv; ++i) pre += wcnt[i];
    if (flag) ccs[pre + myoff] = make_float4(c0.x, c0.y, (float)tid, 0.f);
    if (tid == 0) sS = wcnt[0] + wcnt[1] + wcnt[2] + wcnt[3];
    __syncthreads();
    uint32_t S = sS;

    float best = __builtin_inff();
    float bkf = 0.f;
    for (uint32_t s = 0; s < S; ++s) {
        float4 c = ccs[s];
        float dx = __fsub_rn(px, c.x);
        float dy = __fsub_rn(py, c.y);
        float d2 = __fadd_rn(__fmul_rn(dx, dx), __fmul_rn(dy, dy));  // no fma, match ref
        if (d2 < best) { best = d2; bkf = c.z; }   // first-occurrence (asc k order)
    }
    int bk = (int)bkf;
    closest_out[p] = bkf + 1.0f;
    int seg = (int)segsf[p];
    if (seg >= 24 && seg <= 33) {
        atomicAdd(&counts[(b * (KK + 1) + (bk + 1)) * NC + seg], 1u);
    }
}

// ---------------------------------------- per-instance majority class, n, valid
__global__ void __launch_bounds__(256) k_inst(const uint32_t* __restrict__ counts,
                                              const float* __restrict__ probs_out,
                                              float* __restrict__ ic_out,
                                              float* __restrict__ np_out,
                                              float* __restrict__ va_out) {
    int t = blockIdx.x * 256 + threadIdx.x;
    if (t >= NB * KK) return;
    int b = t / KK, k = t - b * KK;
    const uint32_t* row = counts + (size_t)(b * (KK + 1) + (k + 1)) * NC;
    uint32_t n = 0, mx = 0;
    int am = 0;
#pragma unroll
    for (int c = 0; c < NC; ++c) {
        uint32_t x = row[c];
        n += x;
        if (x > mx) { mx = x; am = c; }
    }
    ic_out[t] = (float)am;
    np_out[t] = (float)n;
    va_out[t] = (n > 0u && probs_out[t] > 0.f) ? 1.f : 0.f;
}

// ---------------------------------------- per-instance softmax-prob sums
template <int USE_STATS>
__global__ void __launch_bounds__(256) k_sums(const float* __restrict__ logits,
                                              const float* __restrict__ segsf,
                                              const float* __restrict__ closestf,
                                              const float* __restrict__ icf,
                                              const float* __restrict__ scomb,
                                              float* __restrict__ sums) {
    __shared__ int ic_l[KK];
    __shared__ float psum[KK + 1];
    int tid = threadIdx.x;
    int p0 = blockIdx.x * 256;
    int b = p0 / HWW;
    if (tid < KK) ic_l[tid] = (int)icf[b * KK + tid];
    if (tid < KK + 1) psum[tid] = 0.f;
    __syncthreads();
    int p = p0 + tid;
    int r = p - b * HWW;
    int seg = (int)segsf[p];
    if (seg >= 24 && seg <= 33) {
        int cl = (int)closestf[p];
        int ic = ic_l[cl - 1];
        const float* base = logits + (size_t)b * NC * HWW + r;
        float pr;
        if (USE_STATS) {
            float lv = base[(size_t)ic * HWW];
            pr = __expf(lv - scomb[p]);
        } else {
            float v[NC];
            float vmax = -3e38f, lv = 0.f;
#pragma unroll
            for (int c = 0; c < NC; ++c) {
                v[c] = base[(size_t)c * HWW];
                vmax = fmaxf(vmax, v[c]);
                if (c == ic) lv = v[c];
            }
            float s = 0.f;
#pragma unroll
            for (int c = 0; c < NC; ++c) s += __expf(v[c] - vmax);
            pr = __expf(lv - vmax) / s;
        }
        atomicAdd(&psum[cl], pr);
    }
    __syncthreads();
    if (tid < KK + 1) {
        float x = psum[tid];
        if (x != 0.f) atomicAdd(&sums[b * (KK + 1) + tid], x);
    }
}

// ---------------------------------------- final seg_prob
__global__ void __launch_bounds__(256) k_segprob(const float* __restrict__ sums,
                                                 const float* __restrict__ np_out,
                                                 float* __restrict__ sp_out) {
    int t = blockIdx.x * 256 + threadIdx.x;
    if (t >= NB * KK) return;
    int b = t / KK, k = t - b * KK;
    float n = np_out[t];
    float s = sums[b * (KK + 1) + k + 1];
    sp_out[t] = (n > 0.f) ? (s / n) : 0.f;
}

extern "C" void kernel_launch(void* const* d_in, const int* in_sizes, int n_in,
                              void* d_out, int out_size, void* d_ws, size_t ws_size,
                              hipStream_t stream) {
    const float* logits = (const float*)d_in[0];
    const float* cmap   = (const float*)d_in[1];
    const float* reg    = (const float*)d_in[2];
    float* out = (float*)d_out;
    float* o_ic   = out;
    float* o_prob = out + NB * KK;
    float* o_sp   = out + 2 * NB * KK;
    float* o_np   = out + 3 * NB * KK;
    float* o_va   = out + 4 * NB * KK;
    float* o_segs = out + 5 * NB * KK;
    float* o_clo  = out + 5 * NB * KK + NB * HWW;

    char* w = (char*)d_ws;
    size_t off = 0;
    auto alloc = [&](size_t bytes) {
        off = (off + 15) & ~((size_t)15);
        void* p = w + off;
        off += bytes;
        return p;
    };
    uint64_t* cand   = (uint64_t*)alloc(sizeof(uint64_t) * NB * CAP);
    uint32_t* cnt    = (uint32_t*)alloc(sizeof(uint32_t) * NB);
    uint32_t* counts = (uint32_t*)alloc(sizeof(uint32_t) * NB * (KK + 1) * NC);
    float* sums      = (float*)alloc(sizeof(float) * NB * (KK + 1));
    float* cxy       = (float*)alloc(sizeof(float) * NB * KK * 2);
    size_t base_need = (off + 15) & ~((size_t)15);
    float* scomb = (float*)(w + base_need);
    int use_stats = (base_need + sizeof(float) * (size_t)NB * HWW) <= ws_size ? 1 : 0;

    k_seg<<<NB * HWW / 2 / 256, 256, 0, stream>>>(logits, o_segs, scomb, cnt, counts, sums, use_stats);
    k_nms<<<NB * (HH / TH) * (WW / TW), 256, 0, stream>>>(cmap, cand, cnt);
    k_topk<<<NB, 1024, 0, stream>>>(cand, cnt, o_prob, cxy);
    k_assign<<<NB * 2048, 256, 0, stream>>>(reg, cxy, o_segs, o_clo, counts);
    k_inst<<<(NB * KK + 255) / 256, 256, 0, stream>>>(counts, o_prob, o_ic, o_np, o_va);
    if (use_stats)
        k_sums<1><<<NB * HWW / 256, 256, 0, stream>>>(logits, o_segs, o_clo, o_ic, scomb, sums);
    else
        k_sums<0><<<NB * HWW / 256, 256, 0, stream>>>(logits, o_segs, o_clo, o_ic, scomb, sums);
    k_segprob<<<(NB * KK + 255) / 256, 256, 0, stream>>>(sums, o_np, o_sp);
}